// Round 6
// baseline (8850.871 us; speedup 1.0000x reference)
//
#include <hip/hip_runtime.h>

#define P_TOT 65536
#define DIM   384
#define KCL   64
#define ITERS 10
#define BPTS  128            // points per block = 8 waves x 16 pts; grid 512
#define WPTS  16             // points per wave
#define BK    16             // centers k-tile depth (double buffered)
#define BKP   17             // padded row (odd stride -> 2-way banks, free)
#define NKT   (DIM / BK)     // 24
#define NPART (P_TOT / BPTS) // 512 per-block partial sum slots

// d_ws (floats): centers[24576] | cnorm[64] | cnt[64] | CW[24576] | labs[int 65536]
// partials[512][64][384] (50.3 MB) lives in d_out (dead until gather overwrites).

// centers0 = points[:64]; cnorm[c] = ||center||^2 ; zero cnt
__global__ __launch_bounds__(384) void init_kernel(const float* __restrict__ x,
                                                   float* __restrict__ centers,
                                                   float* __restrict__ cnorm,
                                                   float* __restrict__ cnt) {
    __shared__ float red[384];
    const int c = blockIdx.x, t = threadIdx.x;
    float v = x[(size_t)c * DIM + t];
    centers[(size_t)c * DIM + t] = v;
    if (t == 0) cnt[c] = 0.f;
    red[t] = v * v;
    __syncthreads();
    if (t < 128) red[t] = red[t] + red[t + 128] + red[t + 256];
    __syncthreads();
    for (int s = 64; s > 0; s >>= 1) {
        if (t < s) red[t] += red[t + s];
        __syncthreads();
    }
    if (t == 0) cnorm[c] = red[0];
}

// ---- lane=cluster GEMM+argmin body. 512 thr = 8 waves x 16 points.
// Lane l owns cluster l. x values are wave-uniform (broadcast loads, no LDS);
// centers come from an 8.7KB double-buffered LDS tile (4 ds_read_b128 / tile).
// Per (point,cluster): k-ascending single-fmac chain => labels bit-identical
// to all prior passing rounds. Produces lab[BPTS] in LDS.
#define WAVE_GEMM_ARGMIN(X, CENTERS, CNORM)                                          \
    const int t    = threadIdx.x;                                                    \
    const int lane = t & 63;                                                         \
    const int wv   = t >> 6;                                                         \
    const int p0   = blockIdx.x * BPTS;                                              \
    const int sc   = t >> 3;          /* staging: cluster row 0..63 */               \
    const int sk   = (t & 7) * 2;     /* staging: k offset 0,2,..,14 */              \
    float acc[WPTS];                                                                 \
    _Pragma("unroll")                                                                \
    for (int i = 0; i < WPTS; ++i) acc[i] = 0.f;                                     \
    const float* xw = (X) + (size_t)(p0 + wv * WPTS) * DIM;                          \
    float2 rcs = *(const float2*)((CENTERS) + (size_t)sc * DIM + sk);                \
    for (int kt = 0; kt < NKT; ++kt) {                                               \
        const int cur = kt & 1;                                                      \
        cb[cur][sc][sk]     = rcs.x;                                                 \
        cb[cur][sc][sk + 1] = rcs.y;                                                 \
        if (kt + 1 < NKT)                                                            \
            rcs = *(const float2*)((CENTERS) + (size_t)sc * DIM + (kt + 1) * BK + sk); \
        __syncthreads();               /* single barrier per tile (2-deep dbuf) */   \
        const int k0 = kt * BK;                                                      \
        const float4 cf0 = *(const float4*)&cb[cur][lane][0];                        \
        const float4 cf1 = *(const float4*)&cb[cur][lane][4];                        \
        const float4 cf2 = *(const float4*)&cb[cur][lane][8];                        \
        const float4 cf3 = *(const float4*)&cb[cur][lane][12];                       \
        _Pragma("unroll")                                                            \
        for (int i = 0; i < WPTS; ++i) {                                             \
            const float* xri = xw + (size_t)i * DIM + k0;                            \
            const float4 a0 = *(const float4*)(xri);                                 \
            const float4 a1 = *(const float4*)(xri + 4);                             \
            const float4 a2 = *(const float4*)(xri + 8);                             \
            const float4 a3 = *(const float4*)(xri + 12);                            \
            acc[i] += a0.x * cf0.x;  acc[i] += a0.y * cf0.y;                         \
            acc[i] += a0.z * cf0.z;  acc[i] += a0.w * cf0.w;                         \
            acc[i] += a1.x * cf1.x;  acc[i] += a1.y * cf1.y;                         \
            acc[i] += a1.z * cf1.z;  acc[i] += a1.w * cf1.w;                         \
            acc[i] += a2.x * cf2.x;  acc[i] += a2.y * cf2.y;                         \
            acc[i] += a2.z * cf2.z;  acc[i] += a2.w * cf2.w;                         \
            acc[i] += a3.x * cf3.x;  acc[i] += a3.y * cf3.y;                         \
            acc[i] += a3.z * cf3.z;  acc[i] += a3.w * cf3.w;                         \
        }                                                                            \
    }                                                                                \
    {                                                                                \
        const float cn = (CNORM)[lane];                                              \
        _Pragma("unroll")                                                            \
        for (int i = 0; i < WPTS; ++i) {                                             \
            float d = cn - 2.0f * acc[i];                                            \
            int bc = lane;                                                           \
            _Pragma("unroll")                                                        \
            for (int m = 1; m < 64; m <<= 1) {  /* global min, lowest idx ties */    \
                const float ov = __shfl_xor(d, m, 64);                               \
                const int   oc = __shfl_xor(bc, m, 64);                              \
                if (ov < d || (ov == d && oc < bc)) { d = ov; bc = oc; }             \
            }                                                                        \
            if (lane == 0) lab[wv * WPTS + i] = bc;                                  \
        }                                                                            \
    }                                                                                \
    __syncthreads();

// Fused assign + accumulate. After argmin: counting sort (3KB LDS), then
// thread t owns dim t and walks the sorted point order with 8-batched loads,
// PLAIN-storing each cluster segment to this block's private partial slot.
// Zero atomics in the flush.
__global__ __launch_bounds__(512, 4) void fused_kernel(const float* __restrict__ x,
                                                       const float* __restrict__ centers,
                                                       const float* __restrict__ cnorm,
                                                       float* __restrict__ partials,
                                                       float* __restrict__ cnt) {
    __shared__ float cb[2][KCL][BKP];   // 8.7 KB
    __shared__ int   lab[BPTS];
    __shared__ int   lcnt[KCL];
    __shared__ int   lstart[KCL + 1];
    __shared__ int   lcur[KCL];
    __shared__ int   order[BPTS];

    if (threadIdx.x < KCL) lcnt[threadIdx.x] = 0;

    WAVE_GEMM_ARGMIN(x, centers, cnorm)

    int myl = -1;
    if (t < BPTS) {
        myl = lab[t];
        atomicAdd(&lcnt[myl], 1);            // native int LDS atomic
    }
    __syncthreads();
    if (t < 64) {                            // wave 0: inclusive shfl scan
        int v = lcnt[t];
        int s = v;
#pragma unroll
        for (int d = 1; d < 64; d <<= 1) {
            int u = __shfl_up(s, d, 64);
            if (t >= d) s += u;
        }
        lstart[t] = s - v;
        lcur[t] = s - v;
        if (t == 63) lstart[64] = s;
    }
    __syncthreads();
    if (t < BPTS) {
        int pos = atomicAdd(&lcur[myl], 1);
        order[pos] = t;
    }
    __syncthreads();

    if (t < DIM) {                           // thread t owns dim t
        const float* xb = x + (size_t)p0 * DIM;
        float* sb = partials + (size_t)blockIdx.x * KCL * DIM;
        for (int c = 0; c < KCL; ++c)        // zero absent clusters only
            if (lcnt[c] == 0) sb[(size_t)c * DIM + t] = 0.f;
        int   curc = lab[order[0]];
        float run  = 0.f;
        for (int j0 = 0; j0 < BPTS; j0 += 8) {
            float v[8]; int cc[8];
#pragma unroll
            for (int u = 0; u < 8; ++u) {    // 8 independent loads in flight
                const int p = order[j0 + u];
                cc[u] = lab[p];
                v[u]  = xb[(size_t)p * DIM + t];
            }
#pragma unroll
            for (int u = 0; u < 8; ++u) {    // uniform branch (order is block-wide)
                if (cc[u] != curc) {
                    sb[(size_t)curc * DIM + t] = run;   // plain store: sorted segment
                    run = 0.f; curc = cc[u];
                }
                run += v[u];
            }
        }
        sb[(size_t)curc * DIM + t] = run;
    }
    if (t < KCL && lcnt[t] > 0) atomicAdd(&cnt[t], (float)lcnt[t]);
}

// labels for the final pass -> global
__global__ __launch_bounds__(512, 4) void label_kernel(const float* __restrict__ x,
                                                       const float* __restrict__ centers,
                                                       const float* __restrict__ cnorm,
                                                       int* __restrict__ labs) {
    __shared__ float cb[2][KCL][BKP];
    __shared__ int   lab[BPTS];

    WAVE_GEMM_ARGMIN(x, centers, cnorm)

    if (t < BPTS) labs[p0 + t] = lab[t];
}

// centers[c] = cnt>0 ? sum over 512 partial slots / cnt : old ; cnorm ; re-zero cnt
__global__ __launch_bounds__(384) void update_kernel(const float* __restrict__ partials,
                                                     float* __restrict__ cnt,
                                                     float* __restrict__ centers,
                                                     float* __restrict__ cnorm) {
    __shared__ float red[384];
    const int c = blockIdx.x, t = threadIdx.x;
    const float* pp = partials + (size_t)c * DIM + t;
    float s0 = 0.f, s1 = 0.f, s2 = 0.f, s3 = 0.f;
    float s4 = 0.f, s5 = 0.f, s6 = 0.f, s7 = 0.f;
    for (int b = 0; b < NPART; b += 8) {     // coalesced across t; 8-way ILP
        s0 += pp[(size_t)(b + 0) * KCL * DIM];
        s1 += pp[(size_t)(b + 1) * KCL * DIM];
        s2 += pp[(size_t)(b + 2) * KCL * DIM];
        s3 += pp[(size_t)(b + 3) * KCL * DIM];
        s4 += pp[(size_t)(b + 4) * KCL * DIM];
        s5 += pp[(size_t)(b + 5) * KCL * DIM];
        s6 += pp[(size_t)(b + 6) * KCL * DIM];
        s7 += pp[(size_t)(b + 7) * KCL * DIM];
    }
    float s = ((s0 + s1) + (s2 + s3)) + ((s4 + s5) + (s6 + s7));
    float n = cnt[c];
    float oldv = centers[(size_t)c * DIM + t];
    float nc = (n > 0.f) ? (s / n) : oldv;
    centers[(size_t)c * DIM + t] = nc;
    red[t] = nc * nc;
    __syncthreads();
    if (t == 0) cnt[c] = 0.f;   // after barrier: all reads of cnt[c] done
    if (t < 128) red[t] = red[t] + red[t + 128] + red[t + 256];
    __syncthreads();
    for (int st = 64; st > 0; st >>= 1) {
        if (t < st) red[t] += red[t + st];
        __syncthreads();
    }
    if (t == 0) cnorm[c] = red[0];
}

// CW[c][j] = b[j] + sum_d centers[c][d] * W[j][d]
__global__ __launch_bounds__(384) void cw_kernel(const float* __restrict__ centers,
                                                 const float* __restrict__ W,
                                                 const float* __restrict__ b,
                                                 float* __restrict__ CW) {
    __shared__ float cs[DIM];
    const int c = blockIdx.x, j = threadIdx.x;
    cs[j] = centers[(size_t)c * DIM + j];
    __syncthreads();
    float acc = b[j];
    const float* wr = W + (size_t)j * DIM;
    for (int d4 = 0; d4 < 96; ++d4) {
        float4 v = *(const float4*)(wr + d4 * 4);
        acc += cs[d4 * 4 + 0] * v.x + cs[d4 * 4 + 1] * v.y
             + cs[d4 * 4 + 2] * v.z + cs[d4 * 4 + 3] * v.w;
    }
    CW[(size_t)c * DIM + j] = acc;
}

// pure-BW gather: out[p][:] = CW[labs[p]][:]
__global__ __launch_bounds__(256) void gather_kernel(const int* __restrict__ labs,
                                                     const float* __restrict__ CW,
                                                     float* __restrict__ out) {
    __shared__ int lab[32];
    const int t = threadIdx.x;
    const int p0 = blockIdx.x * 32;
    if (t < 32) lab[t] = labs[p0 + t];
    __syncthreads();
    const int pp = t >> 3;
    const int j0 = t & 7;
    const float* src = CW + (size_t)lab[pp] * DIM;
    float* dst = out + (size_t)(p0 + pp) * DIM;
#pragma unroll
    for (int r = 0; r < 12; ++r) {
        const int jg = (r * 8 + j0) * 4;
        *(float4*)(dst + jg) = *(const float4*)(src + jg);
    }
}

extern "C" void kernel_launch(void* const* d_in, const int* in_sizes, int n_in,
                              void* d_out, int out_size, void* d_ws, size_t ws_size,
                              hipStream_t stream) {
    const float* x = (const float*)d_in[0];  // fp32 (16,4096,384)
    const float* W = (const float*)d_in[1];  // fp32 (384,384)
    const float* b = (const float*)d_in[2];  // fp32 (384,)
    float* out = (float*)d_out;              // fp32 (16,4096,384)

    float* centers = (float*)d_ws;                 // 64*384
    float* cnorm   = centers + KCL * DIM;          // 64
    float* cnt     = cnorm + KCL;                  // 64
    float* CW      = cnt + KCL;                    // 64*384
    int*   labs    = (int*)(CW + KCL * DIM);       // 65536 ints

    // 512 x 64 x 384 fp32 partial-sum slots = 50.3 MB, carved from d_out
    // (dead scratch until gather_kernel overwrites all of d_out at the end).
    float* partials = (float*)d_out;

    init_kernel<<<KCL, 384, 0, stream>>>(x, centers, cnorm, cnt);
    for (int it = 0; it < ITERS; ++it) {
        fused_kernel<<<P_TOT / BPTS, 512, 0, stream>>>(x, centers, cnorm, partials, cnt);
        update_kernel<<<KCL, 384, 0, stream>>>(partials, cnt, centers, cnorm);
    }
    cw_kernel<<<KCL, 384, 0, stream>>>(centers, W, b, CW);
    label_kernel<<<P_TOT / BPTS, 512, 0, stream>>>(x, centers, cnorm, labs);
    gather_kernel<<<P_TOT / 32, 256, 0, stream>>>(labs, CW, out);
}

// Round 7
// 1019.258 us; speedup vs baseline: 8.6836x; 8.6836x over previous
//
#include <hip/hip_runtime.h>

#define P_TOT 65536
#define DIM   384
#define KCL   64
#define ITERS 10
#define BPTS  256            // points per block (fused / label); grid 256
#define NSB   8              // partial sum buffers (atomic contention /8)
#define BK    32             // k-tile depth (double buffered, 1 barrier/tile)
#define NKT   (DIM / BK)     // 12
#define LKA   36             // A row pad: 36*4=144B, %16==0 (b128-aligned rows)
#define LKB   68             // B row pad (k-major), 272B %16==0

// d_ws layout (floats):
// centers[24576] | cnorm[64] | cnt[64] | CW[24576] | sums[8][24576]  ~= 983 KB
// final labels (int[65536]) alias the sums area (dead after last update).

// centers0 = points[:64]; cnorm[c] = ||center||^2 ; zero cnt + all sum buffers
__global__ __launch_bounds__(384) void init_kernel(const float* __restrict__ x,
                                                   float* __restrict__ centers,
                                                   float* __restrict__ cnorm,
                                                   float* __restrict__ cnt,
                                                   float* __restrict__ sums) {
    __shared__ float red[384];
    const int c = blockIdx.x, t = threadIdx.x;
    float v = x[(size_t)c * DIM + t];
    centers[(size_t)c * DIM + t] = v;
#pragma unroll
    for (int b = 0; b < NSB; ++b) sums[(size_t)b * KCL * DIM + (size_t)c * DIM + t] = 0.f;
    if (t == 0) cnt[c] = 0.f;
    red[t] = v * v;
    __syncthreads();
    if (t < 128) red[t] = red[t] + red[t + 128] + red[t + 256];
    __syncthreads();
    for (int s = 64; s > 0; s >>= 1) {
        if (t < s) red[t] += red[t + s];
        __syncthreads();
    }
    if (t == 0) cnorm[c] = red[0];
}

// ---- GEMM+argmin body: 256 points x 64 clusters, 512 threads, 8pt x 4cl
// per thread. A point-major [pt][k] (1 ds_read_b128 = 4 k of one point,
// 4 distinct chunks/wave -> broadcast); B k-major (1 b128 = 4 clusters at
// one k, conflict-free). 12 LDS reads per 128 FMA -> VALU-bound.
// k strictly ascending, one fmac per k => labels bit-identical to prior
// passing rounds. Produces lab[BPTS] in LDS.
#define GEMM_ARGMIN_BODY(X, CENTERS, CNORM)                                          \
    const int t   = threadIdx.x;                                                     \
    const int cg  = t & 15;          /* clusters cg*4..cg*4+3 */                     \
    const int pg  = t >> 4;          /* 0..31: points pg*8..pg*8+7 */                \
    const int p0  = blockIdx.x * BPTS;                                               \
    const int spt = t >> 1;          /* A staging: point 0..255 */                   \
    const int sah = (t & 1) * 16;    /* A staging: k-half {0,16} */                  \
    const int sbc = t >> 3;          /* B staging: cluster 0..63 */                  \
    const int sbk = (t & 7) * 4;     /* B staging: k offset {0,4,..,28} */           \
    if (t < KCL) scn[t] = (CNORM)[t];                                                \
    float acc[8][4];                                                                 \
    _Pragma("unroll")                                                                \
    for (int i = 0; i < 8; ++i)                                                      \
        _Pragma("unroll")                                                            \
        for (int j = 0; j < 4; ++j) acc[i][j] = 0.f;                                 \
    const float* xrow = (X) + (size_t)(p0 + spt) * DIM;                              \
    const float* crow = (CENTERS) + (size_t)sbc * DIM;                               \
    float4 ra0 = *(const float4*)(xrow + sah);                                       \
    float4 ra1 = *(const float4*)(xrow + sah + 4);                                   \
    float4 ra2 = *(const float4*)(xrow + sah + 8);                                   \
    float4 ra3 = *(const float4*)(xrow + sah + 12);                                  \
    float4 rb  = *(const float4*)(crow + sbk);                                       \
    for (int kt = 0; kt < NKT; ++kt) {                                               \
        const int cur = kt & 1;                                                      \
        *(float4*)&At[cur][spt][sah + 0]  = ra0;                                     \
        *(float4*)&At[cur][spt][sah + 4]  = ra1;                                     \
        *(float4*)&At[cur][spt][sah + 8]  = ra2;                                     \
        *(float4*)&At[cur][spt][sah + 12] = ra3;                                     \
        Bt[cur][sbk + 0][sbc] = rb.x;  Bt[cur][sbk + 1][sbc] = rb.y;                 \
        Bt[cur][sbk + 2][sbc] = rb.z;  Bt[cur][sbk + 3][sbc] = rb.w;                 \
        if (kt + 1 < NKT) {            /* prefetch next tile into regs */            \
            const int k0 = (kt + 1) * BK;                                            \
            ra0 = *(const float4*)(xrow + k0 + sah);                                 \
            ra1 = *(const float4*)(xrow + k0 + sah + 4);                             \
            ra2 = *(const float4*)(xrow + k0 + sah + 8);                             \
            ra3 = *(const float4*)(xrow + k0 + sah + 12);                            \
            rb  = *(const float4*)(crow + k0 + sbk);                                 \
        }                                                                            \
        __syncthreads();               /* single barrier per tile (2-deep dbuf) */   \
        _Pragma("unroll")                                                            \
        for (int kq = 0; kq < 8; ++kq) {                                             \
            float af[8][4];                                                          \
            _Pragma("unroll")                                                        \
            for (int i = 0; i < 8; ++i) {                                            \
                const float4 a4 = *(const float4*)&At[cur][pg * 8 + i][kq * 4];      \
                af[i][0] = a4.x; af[i][1] = a4.y; af[i][2] = a4.z; af[i][3] = a4.w;  \
            }                                                                        \
            _Pragma("unroll")                                                        \
            for (int kk = 0; kk < 4; ++kk) {                                         \
                const float4 bf = *(const float4*)&Bt[cur][kq * 4 + kk][cg * 4];     \
                _Pragma("unroll")                                                    \
                for (int i = 0; i < 8; ++i) {                                        \
                    acc[i][0] += af[i][kk] * bf.x;                                   \
                    acc[i][1] += af[i][kk] * bf.y;                                   \
                    acc[i][2] += af[i][kk] * bf.z;                                   \
                    acc[i][3] += af[i][kk] * bf.w;                                   \
                }                                                                    \
            }                                                                        \
        }                                                                            \
    }                                                                                \
    {                                                                                \
        float cn[4];                                                                 \
        _Pragma("unroll")                                                            \
        for (int j = 0; j < 4; ++j) cn[j] = scn[cg * 4 + j];                         \
        _Pragma("unroll")                                                            \
        for (int i = 0; i < 8; ++i) {                                                \
            float bvv = 3.4e38f; int bc = 0;                                         \
            _Pragma("unroll")                                                        \
            for (int j = 0; j < 4; ++j) {                                            \
                float d = cn[j] - 2.0f * acc[i][j];                                  \
                if (d < bvv) { bvv = d; bc = cg * 4 + j; }  /* lowest idx ties */    \
            }                                                                        \
            _Pragma("unroll")                                                        \
            for (int m = 1; m < 16; m <<= 1) {  /* reduce over 16 owner lanes */     \
                const float ov = __shfl_xor(bvv, m, 64);                             \
                const int   oc = __shfl_xor(bc, m, 64);                              \
                if (ov < bvv || (ov == bvv && oc < bc)) { bvv = ov; bc = oc; }       \
            }                                                                        \
            if ((t & 15) == 0) lab[pg * 8 + i] = bc;                                 \
        }                                                                            \
    }                                                                                \
    __syncthreads();

// Fused assign + accumulate: GEMM/argmin (labels stay in LDS), counting sort,
// sorted-walk register accumulation over L3-warm x rows, flush to NSB partial
// buffers (atomic; 6.3M total, proven-cheap in r5).
__global__ __launch_bounds__(512, 2) void fused_kernel(const float* __restrict__ x,
                                                       const float* __restrict__ centers,
                                                       const float* __restrict__ cnorm,
                                                       float* __restrict__ sums,
                                                       float* __restrict__ cnt) {
    __shared__ float At[2][BPTS][LKA];  // 73.7 KB
    __shared__ float Bt[2][BK][LKB];    // 17.4 KB
    __shared__ float scn[KCL];
    __shared__ int   lab[BPTS];
    __shared__ int   lcnt[KCL];
    __shared__ int   lstart[KCL + 1];
    __shared__ int   lcur[KCL];
    __shared__ int   order[BPTS];

    if (threadIdx.x < KCL) lcnt[threadIdx.x] = 0;

    GEMM_ARGMIN_BODY(x, centers, cnorm)

    int myl = -1;
    if (t < BPTS) {
        myl = lab[t];
        atomicAdd(&lcnt[myl], 1);            // native int LDS atomic
    }
    __syncthreads();
    if (t < 64) {                            // wave 0: inclusive shfl scan
        int v = lcnt[t];
        int s = v;
#pragma unroll
        for (int d = 1; d < 64; d <<= 1) {
            int u = __shfl_up(s, d, 64);
            if (t >= d) s += u;
        }
        lstart[t] = s - v;
        lcur[t] = s - v;
        if (t == 63) lstart[64] = s;
    }
    __syncthreads();
    if (t < BPTS) {
        int pos = atomicAdd(&lcur[myl], 1);
        order[pos] = t;
    }
    __syncthreads();

    if (t < DIM) {                           // thread t owns dim t
        const float* xb = x + (size_t)p0 * DIM;
        float* sb = sums + (size_t)(blockIdx.x & (NSB - 1)) * KCL * DIM;
        int   curc = lab[order[0]];
        float run  = 0.f;
        for (int j0 = 0; j0 < BPTS; j0 += 8) {
            float v[8]; int cc[8];
#pragma unroll
            for (int u = 0; u < 8; ++u) {    // 8 independent loads in flight
                const int p = order[j0 + u];
                cc[u] = lab[p];
                v[u]  = xb[(size_t)p * DIM + t];
            }
#pragma unroll
            for (int u = 0; u < 8; ++u) {    // uniform branch (block-wide data)
                if (cc[u] != curc) {
                    atomicAdd(&sb[curc * DIM + t], run);
                    run = 0.f; curc = cc[u];
                }
                run += v[u];
            }
        }
        atomicAdd(&sb[curc * DIM + t], run);
    }
    if (t < KCL && lcnt[t] > 0) atomicAdd(&cnt[t], (float)lcnt[t]);
}

// labels for the final pass -> global (ws sums area, dead after last update)
__global__ __launch_bounds__(512, 2) void label_kernel(const float* __restrict__ x,
                                                       const float* __restrict__ centers,
                                                       const float* __restrict__ cnorm,
                                                       int* __restrict__ labs) {
    __shared__ float At[2][BPTS][LKA];
    __shared__ float Bt[2][BK][LKB];
    __shared__ float scn[KCL];
    __shared__ int   lab[BPTS];

    GEMM_ARGMIN_BODY(x, centers, cnorm)

    if (t < BPTS) labs[p0 + t] = lab[t];
}

// centers[c] = cnt>0 ? sum(partials)/cnt : old ; cnorm ; re-zero partials/cnt
__global__ __launch_bounds__(384) void update_kernel(float* __restrict__ sums,
                                                     float* __restrict__ cnt,
                                                     float* __restrict__ centers,
                                                     float* __restrict__ cnorm) {
    __shared__ float red[384];
    const int c = blockIdx.x, t = threadIdx.x;
    float s = 0.f;
#pragma unroll
    for (int b = 0; b < NSB; ++b) {
        const size_t idx = (size_t)b * KCL * DIM + (size_t)c * DIM + t;
        s += sums[idx];
        sums[idx] = 0.f;
    }
    float n = cnt[c];
    float oldv = centers[(size_t)c * DIM + t];
    float nc = (n > 0.f) ? (s / n) : oldv;
    centers[(size_t)c * DIM + t] = nc;
    red[t] = nc * nc;
    __syncthreads();
    if (t == 0) cnt[c] = 0.f;   // after barrier: all reads of cnt[c] done
    if (t < 128) red[t] = red[t] + red[t + 128] + red[t + 256];
    __syncthreads();
    for (int st = 64; st > 0; st >>= 1) {
        if (t < st) red[t] += red[t + st];
        __syncthreads();
    }
    if (t == 0) cnorm[c] = red[0];
}

// CW[c][j] = b[j] + sum_d centers[c][d] * W[j][d]
__global__ __launch_bounds__(384) void cw_kernel(const float* __restrict__ centers,
                                                 const float* __restrict__ W,
                                                 const float* __restrict__ b,
                                                 float* __restrict__ CW) {
    __shared__ float cs[DIM];
    const int c = blockIdx.x, j = threadIdx.x;
    cs[j] = centers[(size_t)c * DIM + j];
    __syncthreads();
    float acc = b[j];
    const float* wr = W + (size_t)j * DIM;
    for (int d4 = 0; d4 < 96; ++d4) {
        float4 v = *(const float4*)(wr + d4 * 4);
        acc += cs[d4 * 4 + 0] * v.x + cs[d4 * 4 + 1] * v.y
             + cs[d4 * 4 + 2] * v.z + cs[d4 * 4 + 3] * v.w;
    }
    CW[(size_t)c * DIM + j] = acc;
}

// pure-BW gather: out[p][:] = CW[labs[p]][:]
__global__ __launch_bounds__(256) void gather_kernel(const int* __restrict__ labs,
                                                     const float* __restrict__ CW,
                                                     float* __restrict__ out) {
    __shared__ int lab[32];
    const int t = threadIdx.x;
    const int p0 = blockIdx.x * 32;
    if (t < 32) lab[t] = labs[p0 + t];
    __syncthreads();
    const int pp = t >> 3;
    const int j0 = t & 7;
    const float* src = CW + (size_t)lab[pp] * DIM;
    float* dst = out + (size_t)(p0 + pp) * DIM;
#pragma unroll
    for (int r = 0; r < 12; ++r) {
        const int jg = (r * 8 + j0) * 4;
        *(float4*)(dst + jg) = *(const float4*)(src + jg);
    }
}

extern "C" void kernel_launch(void* const* d_in, const int* in_sizes, int n_in,
                              void* d_out, int out_size, void* d_ws, size_t ws_size,
                              hipStream_t stream) {
    const float* x = (const float*)d_in[0];  // fp32 (16,4096,384)
    const float* W = (const float*)d_in[1];  // fp32 (384,384)
    const float* b = (const float*)d_in[2];  // fp32 (384,)
    float* out = (float*)d_out;              // fp32 (16,4096,384)

    float* centers = (float*)d_ws;                 // 64*384
    float* cnorm   = centers + KCL * DIM;          // 64
    float* cnt     = cnorm + KCL;                  // 64
    float* CW      = cnt + KCL;                    // 64*384
    float* sums    = CW + KCL * DIM;               // 8 * 64*384
    int* labs      = (int*)sums;                   // aliases sums (dead after loop)

    init_kernel<<<KCL, 384, 0, stream>>>(x, centers, cnorm, cnt, sums);
    for (int it = 0; it < ITERS; ++it) {
        fused_kernel<<<P_TOT / BPTS, 512, 0, stream>>>(x, centers, cnorm, sums, cnt);
        update_kernel<<<KCL, 384, 0, stream>>>(sums, cnt, centers, cnorm);
    }
    cw_kernel<<<KCL, 384, 0, stream>>>(centers, W, b, CW);
    label_kernel<<<P_TOT / BPTS, 512, 0, stream>>>(x, centers, cnorm, labs);
    gather_kernel<<<P_TOT / 32, 256, 0, stream>>>(labs, CW, out);
}